// Round 5
// baseline (2295.406 us; speedup 1.0000x reference)
//
#include <hip/hip_runtime.h>

// ---------------------------------------------------------------------------
// GCN link predictor: 3x GCNConv (128->256->256->128) + edge dot-product head.
// N=100000 nodes, E=1.6M edges, L=500k label pairs.
// Pipeline: dtype-probe -> weight upconvert -> degree hist -> dinv -> scan ->
//           CSR fill -> [GEMM -> gather-AGG] x3 -> predictor (fp32 out).
// R3: output is FP32 (reference returns jnp.float32; bf16-packed writes in R2
//     produced the telltale max|ref[2i+1]-ref[i]| ~ 6.4e-5 error signature).
// R4: resubmit unchanged (R3 never ran — broker timeout).
// ---------------------------------------------------------------------------

__device__ __forceinline__ float bf2f(unsigned short u) {
  union { unsigned int i; float f; } v; v.i = ((unsigned int)u) << 16; return v.f;
}

// --- dtype probe: even bf16-view elements of fp32 data have random exponents.
__global__ void k_detect(const unsigned short* __restrict__ xh, int* flag) {
  __shared__ int cnt_s;
  if (threadIdx.x == 0) cnt_s = 0;
  __syncthreads();
  int huge = 0;
  for (int j = 0; j < 16; ++j) {
    unsigned short u = xh[2 * (threadIdx.x * 16 + j)];
    int e = (u >> 7) & 0xFF;
    if (e > 137) huge++;                 // |v| > 2^10: impossible for N(0,1) bf16
  }
  atomicAdd(&cnt_s, huge);
  __syncthreads();
  if (threadIdx.x == 0) flag[0] = (cnt_s > 512) ? 1 : 0;   // 1 => fp32 storage
}

__global__ void k_convert(const void* __restrict__ src, float* __restrict__ dst,
                          int n, const int* __restrict__ flagp) {
  const int fp32 = flagp[0];
  int i = blockIdx.x * blockDim.x + threadIdx.x;
  const int stride = gridDim.x * blockDim.x;
  if (fp32) {
    const float* s = (const float*)src;
    for (; i < n; i += stride) dst[i] = s[i];
  } else {
    const unsigned short* s = (const unsigned short*)src;
    for (; i < n; i += stride) dst[i] = bf2f(s[i]);
  }
}

__global__ void k_deg(const int* __restrict__ dst, int E, int* __restrict__ cnt) {
  int i = blockIdx.x * blockDim.x + threadIdx.x;
  const int stride = gridDim.x * blockDim.x;
  for (; i < E; i += stride) atomicAdd(&cnt[dst[i]], 1);
}

__global__ void k_dinv(const int* __restrict__ cnt, float* __restrict__ dinv, int N) {
  int i = blockIdx.x * blockDim.x + threadIdx.x;
  if (i < N) dinv[i] = 1.0f / sqrtf((float)(cnt[i] + 1));   // +1 self-loop
}

// single-block exclusive scan: per-thread chunk totals -> block scan -> rewrite
__global__ void k_scan(const int* __restrict__ cnt, int* __restrict__ rowptr, int n) {
  __shared__ int s[1024];
  const int t = threadIdx.x;
  const int chunk = (n + 1023) >> 10;
  const int b = t * chunk;
  const int e = min(b + chunk, n);
  int sum = 0;
  for (int i = b; i < e; ++i) sum += cnt[i];
  s[t] = sum;
  __syncthreads();
  for (int off = 1; off < 1024; off <<= 1) {
    int add = (t >= off) ? s[t - off] : 0;
    __syncthreads();
    s[t] += add;
    __syncthreads();
  }
  int run = s[t] - sum;                      // exclusive prefix of this chunk
  for (int i = b; i < e; ++i) { rowptr[i] = run; run += cnt[i]; }
  if (t == 1023) rowptr[n] = s[1023];
}

__global__ void k_fill(const int* __restrict__ src, const int* __restrict__ dst, int E,
                       const int* __restrict__ rowptr, int* __restrict__ cursor,
                       int* __restrict__ csr_src) {
  int i = blockIdx.x * blockDim.x + threadIdx.x;
  const int stride = gridDim.x * blockDim.x;
  for (; i < E; i += stride) {
    const int d = dst[i];
    const int pos = rowptr[d] + atomicAdd(&cursor[d], 1);
    csr_src[pos] = src[i];
  }
}

// --- tiled fp32 GEMM: out[N][FOUT] = in[N][Fin] @ W[Fin][FOUT]
// block: 64 rows x FOUT cols; K-tile 32; LDS = 32*FOUT*4 + 32*64*4 <= 40KB.
template <int FOUT>
__global__ __launch_bounds__(256) void k_gemm(
    const float* __restrict__ inF, const unsigned short* __restrict__ inB,
    const int* __restrict__ flagp, int Fin, int N,
    const float* __restrict__ W, float* __restrict__ out) {
  constexpr int NJ = FOUT / 64;
  __shared__ float Ws[32 * FOUT];
  __shared__ float XsT[32 * 64];            // [k][r] -> broadcast reads
  const int t = threadIdx.x;
  const int r0 = blockIdx.x * 64;
  const int tc = t & 63;
  const int tr = t >> 6;
  const int fp32 = flagp ? flagp[0] : 1;

  float acc[16][NJ];
#pragma unroll
  for (int i = 0; i < 16; ++i)
#pragma unroll
    for (int j = 0; j < NJ; ++j) acc[i][j] = 0.f;

  for (int k0 = 0; k0 < Fin; k0 += 32) {
    {   // stage X^T
      const int r = t >> 2;
      const int ks = (t & 3) * 8;
      const int grow = r0 + r;
      const size_t gbase = (size_t)grow * Fin + k0 + ks;
#pragma unroll
      for (int j = 0; j < 8; ++j) {
        float v = 0.f;
        if (grow < N) v = fp32 ? inF[gbase + j] : bf2f(inB[gbase + j]);
        XsT[(ks + j) * 64 + r] = v;
      }
    }
    {   // stage W tile
#pragma unroll
      for (int p = 0; p < FOUT / 8; ++p) {
        const int idx = t + 256 * p;        // over [32][FOUT] row-major
        const int k = idx / FOUT, c = idx % FOUT;
        Ws[idx] = W[(size_t)(k0 + k) * FOUT + c];
      }
    }
    __syncthreads();
    for (int k = 0; k < 32; ++k) {
      const float4* xr = reinterpret_cast<const float4*>(&XsT[k * 64 + tr * 16]);
      const float4 a0 = xr[0], a1 = xr[1], a2 = xr[2], a3 = xr[3];
      const float xv[16] = {a0.x, a0.y, a0.z, a0.w, a1.x, a1.y, a1.z, a1.w,
                            a2.x, a2.y, a2.z, a2.w, a3.x, a3.y, a3.z, a3.w};
      float wv[NJ];
#pragma unroll
      for (int j = 0; j < NJ; ++j) wv[j] = Ws[k * FOUT + tc + 64 * j];
#pragma unroll
      for (int i = 0; i < 16; ++i)
#pragma unroll
        for (int j = 0; j < NJ; ++j) acc[i][j] = fmaf(xv[i], wv[j], acc[i][j]);
    }
    __syncthreads();
  }
#pragma unroll
  for (int i = 0; i < 16; ++i) {
    const int r = r0 + tr * 16 + i;
    if (r < N) {
#pragma unroll
      for (int j = 0; j < NJ; ++j)
        out[(size_t)r * FOUT + tc + 64 * j] = acc[i][j];
    }
  }
}

// --- gather aggregation: H[d] = sum_{s in CSR[d]} T[s]*dinv[s]*dinv[d]
//                                + T[d]*dinv[d]^2 + bias
template <int FOUT>
__global__ __launch_bounds__(256) void k_agg(
    const float* __restrict__ T, float* __restrict__ H,
    const float* __restrict__ dinv, const int* __restrict__ rowptr,
    const int* __restrict__ csr_src, const float* __restrict__ bias, int N) {
  constexpr int NPB = 256 / FOUT;
  const int t = threadIdx.x;
  const int node = blockIdx.x * NPB + t / FOUT;
  const int col = t % FOUT;
  if (node >= N) return;
  const float di = dinv[node];
  float acc = T[(size_t)node * FOUT + col] * di * di;
  const int jb = rowptr[node], je = rowptr[node + 1];
  for (int j = jb; j < je; ++j) {
    const int s = csr_src[j];
    const float nrm = dinv[s] * di;
    acc = fmaf(T[(size_t)s * FOUT + col], nrm, acc);
  }
  H[(size_t)node * FOUT + col] = acc + bias[col];
}

// --- predictor: out[i] = sum_f H[a][f]*H[b][f]*Wp[f] + bp   (fp32 out)
__global__ __launch_bounds__(256) void k_pred(
    const float* __restrict__ H, const int* __restrict__ eli, int L,
    const float* __restrict__ Wp, const float* __restrict__ bp,
    float* __restrict__ out) {
  __shared__ float wp_s[128];
  if (threadIdx.x < 128) wp_s[threadIdx.x] = Wp[threadIdx.x];
  __syncthreads();
  const int i = blockIdx.x * 256 + threadIdx.x;
  if (i >= L) return;
  const int a = eli[i], b = eli[L + i];
  const float4* ha = reinterpret_cast<const float4*>(H + (size_t)a * 128);
  const float4* hb = reinterpret_cast<const float4*>(H + (size_t)b * 128);
  const float4* wp4 = reinterpret_cast<const float4*>(wp_s);
  float acc = 0.f;
#pragma unroll
  for (int q = 0; q < 32; ++q) {
    const float4 x = ha[q], y = hb[q], w = wp4[q];
    acc += x.x * y.x * w.x + x.y * y.y * w.y + x.z * y.z * w.z + x.w * y.w * w.w;
  }
  out[i] = acc + bp[0];
}

extern "C" void kernel_launch(void* const* d_in, const int* in_sizes, int n_in,
                              void* d_out, int out_size, void* d_ws, size_t ws_size,
                              hipStream_t stream) {
  (void)n_in; (void)out_size; (void)ws_size;
  const void* x   = d_in[0];
  const int*  ei  = (const int*)d_in[1];   // [2][E]: src row 0, dst row 1
  const int*  eli = (const int*)d_in[2];   // [2][L]
  const int N = in_sizes[0] / 128;
  const int E = in_sizes[1] / 2;
  const int L = in_sizes[2] / 2;

  // workspace carve-out (256B aligned)
  char* p = (char*)d_ws;
  auto alloc = [&](size_t bytes) -> char* {
    char* r = p; p += (bytes + 255) & ~(size_t)255; return r;
  };
  int*   flag    = (int*)  alloc(256);
  float* wf      = (float*)alloc((size_t)131841 * 4);   // all weights fp32
  int*   cnt     = (int*)  alloc((size_t)N * 4);
  int*   rowptr  = (int*)  alloc(((size_t)N + 1) * 4);
  int*   cursor  = (int*)  alloc((size_t)N * 4);
  float* dinv    = (float*)alloc((size_t)N * 4);
  int*   csr_src = (int*)  alloc((size_t)E * 4);
  float* bufA    = (float*)alloc((size_t)N * 256 * 4);
  float* bufB    = (float*)alloc((size_t)N * 256 * 4);

  // weight layout inside wf (float offsets)
  const int OW1 = 0, OB1 = 32768, OW2 = 33024, OB2 = 98560,
            OW3 = 98816, OB3 = 131584, OWP = 131712, OBP = 131840;

  hipMemsetAsync(flag, 0, 256, stream);
  hipMemsetAsync(cnt, 0, (size_t)N * 4, stream);
  hipMemsetAsync(cursor, 0, (size_t)N * 4, stream);

  k_detect<<<1, 256, 0, stream>>>((const unsigned short*)x, flag);

  const int   widx[8] = {3, 4, 5, 6, 7, 8, 9, 10};
  const int   woff[8] = {OW1, OB1, OW2, OB2, OW3, OB3, OWP, OBP};
  const int   wcnt[8] = {32768, 256, 65536, 256, 32768, 128, 128, 1};
  for (int i = 0; i < 8; ++i) {
    int grid = (wcnt[i] + 255) / 256; if (grid > 256) grid = 256;
    k_convert<<<grid, 256, 0, stream>>>(d_in[widx[i]], wf + woff[i], wcnt[i], flag);
  }

  k_deg<<<2048, 256, 0, stream>>>(ei + E, E, cnt);
  k_dinv<<<(N + 255) / 256, 256, 0, stream>>>(cnt, dinv, N);
  k_scan<<<1, 1024, 0, stream>>>(cnt, rowptr, N);
  k_fill<<<2048, 256, 0, stream>>>(ei, ei + E, E, rowptr, cursor, csr_src);

  const int ggrid = (N + 63) / 64;
  // layer 1: x[ N x 128 ] @ W1 -> bufA; agg -> bufB
  k_gemm<256><<<ggrid, 256, 0, stream>>>((const float*)x, (const unsigned short*)x,
                                         flag, 128, N, wf + OW1, bufA);
  k_agg<256><<<N, 256, 0, stream>>>(bufA, bufB, dinv, rowptr, csr_src, wf + OB1, N);
  // layer 2: bufB[ N x 256 ] @ W2 -> bufA; agg -> bufB
  k_gemm<256><<<ggrid, 256, 0, stream>>>(bufB, nullptr, nullptr, 256, N, wf + OW2, bufA);
  k_agg<256><<<N, 256, 0, stream>>>(bufA, bufB, dinv, rowptr, csr_src, wf + OB2, N);
  // layer 3: bufB[ N x 256 ] @ W3 -> bufA[N x 128]; agg -> bufB[N x 128]
  k_gemm<128><<<ggrid, 256, 0, stream>>>(bufB, nullptr, nullptr, 256, N, wf + OW3, bufA);
  k_agg<128><<<(N + 1) / 2, 256, 0, stream>>>(bufA, bufB, dinv, rowptr, csr_src,
                                              wf + OB3, N);
  // predictor (fp32 out)
  k_pred<<<(L + 255) / 256, 256, 0, stream>>>(bufB, eli, L, wf + OWP, wf + OBP,
                                              (float*)d_out);
}

// Round 8
// 1475.610 us; speedup vs baseline: 1.5556x; 1.5556x over previous
//
#include <hip/hip_runtime.h>

// ---------------------------------------------------------------------------
// GCN link predictor: 3x GCNConv (128->256->256->128) + edge dot-product head.
// R5: agg rewrite (wave-per-node, float4 rows, x4 edge unroll, streamed norms)
//     + layer-1 reorder: h1 = (S X) W1 + b1   [S(XW)=(SX)W, bias after agg]
//     -> layer-1 agg gathers 128 cols instead of 256.
// R6/R7: resubmit unchanged (R5 never ran — broker timeouts).
// Buffers ping-pong: conv(x)->A, agg A->B, G1 B->A(+b1), G2 A->B,
//                    agg B->A(+b2), G3 A->B, agg B->A(+b3), pred(A).
// ---------------------------------------------------------------------------

__device__ __forceinline__ float bf2f(unsigned short u) {
  union { unsigned int i; float f; } v; v.i = ((unsigned int)u) << 16; return v.f;
}
__device__ __forceinline__ float4 f4fma(float4 a, float s, float4 c) {
  c.x = fmaf(a.x, s, c.x); c.y = fmaf(a.y, s, c.y);
  c.z = fmaf(a.z, s, c.z); c.w = fmaf(a.w, s, c.w); return c;
}
__device__ __forceinline__ float2 f2fma(float2 a, float s, float2 c) {
  c.x = fmaf(a.x, s, c.x); c.y = fmaf(a.y, s, c.y); return c;
}

// --- dtype probe: even bf16-view elements of fp32 data have random exponents.
__global__ void k_detect(const unsigned short* __restrict__ xh, int* flag) {
  __shared__ int cnt_s;
  if (threadIdx.x == 0) cnt_s = 0;
  __syncthreads();
  int huge = 0;
  for (int j = 0; j < 16; ++j) {
    unsigned short u = xh[2 * (threadIdx.x * 16 + j)];
    int e = (u >> 7) & 0xFF;
    if (e > 137) huge++;                 // |v| > 2^10: impossible for N(0,1) bf16
  }
  atomicAdd(&cnt_s, huge);
  __syncthreads();
  if (threadIdx.x == 0) flag[0] = (cnt_s > 512) ? 1 : 0;   // 1 => fp32 storage
}

__global__ void k_convert(const void* __restrict__ src, float* __restrict__ dst,
                          int n, const int* __restrict__ flagp) {
  const int fp32 = flagp[0];
  int i = blockIdx.x * blockDim.x + threadIdx.x;
  const int stride = gridDim.x * blockDim.x;
  if (fp32) {
    const float* s = (const float*)src;
    for (; i < n; i += stride) dst[i] = s[i];
  } else {
    const unsigned short* s = (const unsigned short*)src;
    for (; i < n; i += stride) dst[i] = bf2f(s[i]);
  }
}

__global__ void k_deg(const int* __restrict__ dst, int E, int* __restrict__ cnt) {
  int i = blockIdx.x * blockDim.x + threadIdx.x;
  const int stride = gridDim.x * blockDim.x;
  for (; i < E; i += stride) atomicAdd(&cnt[dst[i]], 1);
}

__global__ void k_dinv(const int* __restrict__ cnt, float* __restrict__ dinv, int N) {
  int i = blockIdx.x * blockDim.x + threadIdx.x;
  if (i < N) dinv[i] = 1.0f / sqrtf((float)(cnt[i] + 1));   // +1 self-loop
}

// single-block exclusive scan: per-thread chunk totals -> block scan -> rewrite
__global__ void k_scan(const int* __restrict__ cnt, int* __restrict__ rowptr, int n) {
  __shared__ int s[1024];
  const int t = threadIdx.x;
  const int chunk = (n + 1023) >> 10;
  const int b = t * chunk;
  const int e = min(b + chunk, n);
  int sum = 0;
  for (int i = b; i < e; ++i) sum += cnt[i];
  s[t] = sum;
  __syncthreads();
  for (int off = 1; off < 1024; off <<= 1) {
    int add = (t >= off) ? s[t - off] : 0;
    __syncthreads();
    s[t] += add;
    __syncthreads();
  }
  int run = s[t] - sum;                      // exclusive prefix of this chunk
  for (int i = b; i < e; ++i) { rowptr[i] = run; run += cnt[i]; }
  if (t == 1023) rowptr[n] = s[1023];
}

// fill CSR adjacency; also stream out dinv[src] so the agg inner loop never
// does a random scalar gather.
__global__ void k_fill(const int* __restrict__ src, const int* __restrict__ dst, int E,
                       const int* __restrict__ rowptr, int* __restrict__ cursor,
                       const float* __restrict__ dinv,
                       int* __restrict__ csr_src, float* __restrict__ csr_nrm) {
  int i = blockIdx.x * blockDim.x + threadIdx.x;
  const int stride = gridDim.x * blockDim.x;
  for (; i < E; i += stride) {
    const int d = dst[i];
    const int s = src[i];
    const int pos = rowptr[d] + atomicAdd(&cursor[d], 1);
    csr_src[pos] = s;
    csr_nrm[pos] = dinv[s];
  }
}

// --- tiled fp32 GEMM: out[N][FOUT] = in[N][Fin] @ W[Fin][FOUT] (+ bias)
template <int FOUT>
__global__ __launch_bounds__(256) void k_gemm(
    const float* __restrict__ in, int Fin, int N,
    const float* __restrict__ W, const float* __restrict__ bias,
    float* __restrict__ out) {
  constexpr int NJ = FOUT / 64;
  __shared__ float Ws[32 * FOUT];
  __shared__ float XsT[32 * 64];            // [k][r] -> broadcast reads
  const int t = threadIdx.x;
  const int r0 = blockIdx.x * 64;
  const int tc = t & 63;
  const int tr = t >> 6;

  float acc[16][NJ];
#pragma unroll
  for (int i = 0; i < 16; ++i)
#pragma unroll
    for (int j = 0; j < NJ; ++j) acc[i][j] = 0.f;

  for (int k0 = 0; k0 < Fin; k0 += 32) {
    {   // stage X^T
      const int r = t >> 2;
      const int ks = (t & 3) * 8;
      const int grow = r0 + r;
      const size_t gbase = (size_t)grow * Fin + k0 + ks;
#pragma unroll
      for (int j = 0; j < 8; ++j)
        XsT[(ks + j) * 64 + r] = (grow < N) ? in[gbase + j] : 0.f;
    }
    {   // stage W tile
#pragma unroll
      for (int p = 0; p < FOUT / 8; ++p) {
        const int idx = t + 256 * p;        // over [32][FOUT] row-major
        const int k = idx / FOUT, c = idx % FOUT;
        Ws[idx] = W[(size_t)(k0 + k) * FOUT + c];
      }
    }
    __syncthreads();
    for (int k = 0; k < 32; ++k) {
      const float4* xr = reinterpret_cast<const float4*>(&XsT[k * 64 + tr * 16]);
      const float4 a0 = xr[0], a1 = xr[1], a2 = xr[2], a3 = xr[3];
      const float xv[16] = {a0.x, a0.y, a0.z, a0.w, a1.x, a1.y, a1.z, a1.w,
                            a2.x, a2.y, a2.z, a2.w, a3.x, a3.y, a3.z, a3.w};
      float wv[NJ];
#pragma unroll
      for (int j = 0; j < NJ; ++j) wv[j] = Ws[k * FOUT + tc + 64 * j];
#pragma unroll
      for (int i = 0; i < 16; ++i)
#pragma unroll
        for (int j = 0; j < NJ; ++j) acc[i][j] = fmaf(xv[i], wv[j], acc[i][j]);
    }
    __syncthreads();
  }
#pragma unroll
  for (int i = 0; i < 16; ++i) {
    const int r = r0 + tr * 16 + i;
    if (r < N) {
#pragma unroll
      for (int j = 0; j < NJ; ++j) {
        const int c = tc + 64 * j;
        out[(size_t)r * FOUT + c] = acc[i][j] + (bias ? bias[c] : 0.f);
      }
    }
  }
}

// --- gather aggregation, wave-per-node, x4 unrolled for MLP:
// H[d] = sum_{s in CSR[d]} T[s]*nrm[s]*di + T[d]*di^2 (+ bias)
template <int FOUT>
__global__ __launch_bounds__(256) void k_agg(
    const float* __restrict__ T, float* __restrict__ H,
    const float* __restrict__ dinv, const int* __restrict__ rowptr,
    const int* __restrict__ csr_src, const float* __restrict__ csr_nrm,
    const float* __restrict__ bias, int N) {
  const int lane = threadIdx.x & 63;
  const int node = blockIdx.x * 4 + (threadIdx.x >> 6);
  if (node >= N) return;
  const float di = dinv[node];
  const int jb = rowptr[node], je = rowptr[node + 1];

  if constexpr (FOUT == 256) {
    const float4* __restrict__ B = (const float4*)T;      // 64 float4 / row
    float4 acc = B[(size_t)node * 64 + lane];
    acc.x *= di * di; acc.y *= di * di; acc.z *= di * di; acc.w *= di * di;
    int j = jb;
    for (; j + 4 <= je; j += 4) {
      const int s0 = csr_src[j], s1 = csr_src[j + 1],
                s2 = csr_src[j + 2], s3 = csr_src[j + 3];
      const float n0 = csr_nrm[j] * di, n1 = csr_nrm[j + 1] * di,
                  n2 = csr_nrm[j + 2] * di, n3 = csr_nrm[j + 3] * di;
      const float4 r0 = B[(size_t)s0 * 64 + lane];
      const float4 r1 = B[(size_t)s1 * 64 + lane];
      const float4 r2 = B[(size_t)s2 * 64 + lane];
      const float4 r3 = B[(size_t)s3 * 64 + lane];
      acc = f4fma(r0, n0, acc); acc = f4fma(r1, n1, acc);
      acc = f4fma(r2, n2, acc); acc = f4fma(r3, n3, acc);
    }
    for (; j < je; ++j)
      acc = f4fma(B[(size_t)csr_src[j] * 64 + lane], csr_nrm[j] * di, acc);
    if (bias) {
      const float4 b = ((const float4*)bias)[lane];
      acc.x += b.x; acc.y += b.y; acc.z += b.z; acc.w += b.w;
    }
    ((float4*)H)[(size_t)node * 64 + lane] = acc;
  } else {                                   // FOUT == 128
    const float2* __restrict__ B = (const float2*)T;      // 64 float2 / row
    float2 acc = B[(size_t)node * 64 + lane];
    acc.x *= di * di; acc.y *= di * di;
    int j = jb;
    for (; j + 4 <= je; j += 4) {
      const int s0 = csr_src[j], s1 = csr_src[j + 1],
                s2 = csr_src[j + 2], s3 = csr_src[j + 3];
      const float n0 = csr_nrm[j] * di, n1 = csr_nrm[j + 1] * di,
                  n2 = csr_nrm[j + 2] * di, n3 = csr_nrm[j + 3] * di;
      const float2 r0 = B[(size_t)s0 * 64 + lane];
      const float2 r1 = B[(size_t)s1 * 64 + lane];
      const float2 r2 = B[(size_t)s2 * 64 + lane];
      const float2 r3 = B[(size_t)s3 * 64 + lane];
      acc = f2fma(r0, n0, acc); acc = f2fma(r1, n1, acc);
      acc = f2fma(r2, n2, acc); acc = f2fma(r3, n3, acc);
    }
    for (; j < je; ++j)
      acc = f2fma(B[(size_t)csr_src[j] * 64 + lane], csr_nrm[j] * di, acc);
    if (bias) {
      const float2 b = ((const float2*)bias)[lane];
      acc.x += b.x; acc.y += b.y;
    }
    ((float2*)H)[(size_t)node * 64 + lane] = acc;
  }
}

// --- predictor: out[i] = sum_f H[a][f]*H[b][f]*Wp[f] + bp   (fp32 out)
__global__ __launch_bounds__(256) void k_pred(
    const float* __restrict__ H, const int* __restrict__ eli, int L,
    const float* __restrict__ Wp, const float* __restrict__ bp,
    float* __restrict__ out) {
  __shared__ float wp_s[128];
  if (threadIdx.x < 128) wp_s[threadIdx.x] = Wp[threadIdx.x];
  __syncthreads();
  const int i = blockIdx.x * 256 + threadIdx.x;
  if (i >= L) return;
  const int a = eli[i], b = eli[L + i];
  const float4* ha = reinterpret_cast<const float4*>(H + (size_t)a * 128);
  const float4* hb = reinterpret_cast<const float4*>(H + (size_t)b * 128);
  const float4* wp4 = reinterpret_cast<const float4*>(wp_s);
  float acc = 0.f;
#pragma unroll
  for (int q = 0; q < 32; ++q) {
    const float4 x = ha[q], y = hb[q], w = wp4[q];
    acc += x.x * y.x * w.x + x.y * y.y * w.y + x.z * y.z * w.z + x.w * y.w * w.w;
  }
  out[i] = acc + bp[0];
}

extern "C" void kernel_launch(void* const* d_in, const int* in_sizes, int n_in,
                              void* d_out, int out_size, void* d_ws, size_t ws_size,
                              hipStream_t stream) {
  (void)n_in; (void)out_size; (void)ws_size;
  const void* x   = d_in[0];
  const int*  ei  = (const int*)d_in[1];   // [2][E]: src row 0, dst row 1
  const int*  eli = (const int*)d_in[2];   // [2][L]
  const int N = in_sizes[0] / 128;
  const int E = in_sizes[1] / 2;
  const int L = in_sizes[2] / 2;

  // workspace carve-out (256B aligned)
  char* p = (char*)d_ws;
  auto alloc = [&](size_t bytes) -> char* {
    char* r = p; p += (bytes + 255) & ~(size_t)255; return r;
  };
  int*   flag    = (int*)  alloc(256);
  float* wf      = (float*)alloc((size_t)131841 * 4);   // all weights fp32
  int*   cnt     = (int*)  alloc((size_t)N * 4);
  int*   rowptr  = (int*)  alloc(((size_t)N + 1) * 4);
  int*   cursor  = (int*)  alloc((size_t)N * 4);
  float* dinv    = (float*)alloc((size_t)N * 4);
  int*   csr_src = (int*)  alloc((size_t)E * 4);
  float* csr_nrm = (float*)alloc((size_t)E * 4);
  float* bufA    = (float*)alloc((size_t)N * 256 * 4);
  float* bufB    = (float*)alloc((size_t)N * 256 * 4);

  // weight layout inside wf (float offsets)
  const int OW1 = 0, OB1 = 32768, OW2 = 33024, OB2 = 98560,
            OW3 = 98816, OB3 = 131584, OWP = 131712, OBP = 131840;

  hipMemsetAsync(flag, 0, 256, stream);
  hipMemsetAsync(cnt, 0, (size_t)N * 4, stream);
  hipMemsetAsync(cursor, 0, (size_t)N * 4, stream);

  k_detect<<<1, 256, 0, stream>>>((const unsigned short*)x, flag);

  const int   widx[8] = {3, 4, 5, 6, 7, 8, 9, 10};
  const int   woff[8] = {OW1, OB1, OW2, OB2, OW3, OB3, OWP, OBP};
  const int   wcnt[8] = {32768, 256, 65536, 256, 32768, 128, 128, 1};
  for (int i = 0; i < 8; ++i) {
    int grid = (wcnt[i] + 255) / 256; if (grid > 256) grid = 256;
    k_convert<<<grid, 256, 0, stream>>>(d_in[widx[i]], wf + woff[i], wcnt[i], flag);
  }
  // x -> fp32 in bufA
  k_convert<<<2048, 256, 0, stream>>>(x, bufA, N * 128, flag);

  k_deg<<<2048, 256, 0, stream>>>(ei + E, E, cnt);
  k_dinv<<<(N + 255) / 256, 256, 0, stream>>>(cnt, dinv, N);
  k_scan<<<1, 1024, 0, stream>>>(cnt, rowptr, N);
  k_fill<<<2048, 256, 0, stream>>>(ei, ei + E, E, rowptr, cursor, dinv,
                                   csr_src, csr_nrm);

  const int ggrid = (N + 63) / 64;
  const int agrid = (N + 3) / 4;
  // layer 1 (reordered): agg(x) on 128 cols, then GEMM + b1
  k_agg<128><<<agrid, 256, 0, stream>>>(bufA, bufB, dinv, rowptr, csr_src,
                                        csr_nrm, nullptr, N);
  k_gemm<256><<<ggrid, 256, 0, stream>>>(bufB, 128, N, wf + OW1, wf + OB1, bufA);
  // layer 2: GEMM then agg + b2
  k_gemm<256><<<ggrid, 256, 0, stream>>>(bufA, 256, N, wf + OW2, nullptr, bufB);
  k_agg<256><<<agrid, 256, 0, stream>>>(bufB, bufA, dinv, rowptr, csr_src,
                                        csr_nrm, wf + OB2, N);
  // layer 3: GEMM then agg + b3
  k_gemm<128><<<ggrid, 256, 0, stream>>>(bufA, 256, N, wf + OW3, nullptr, bufB);
  k_agg<128><<<agrid, 256, 0, stream>>>(bufB, bufA, dinv, rowptr, csr_src,
                                        csr_nrm, wf + OB3, N);
  // predictor (fp32 out)
  k_pred<<<(L + 255) / 256, 256, 0, stream>>>(bufA, eli, L, wf + OWP, wf + OBP,
                                              (float*)d_out);
}

// Round 10
// 1221.004 us; speedup vs baseline: 1.8799x; 1.2085x over previous
//
#include <hip/hip_runtime.h>

// ---------------------------------------------------------------------------
// GCN link predictor: 3x GCNConv (128->256->256->128) + edge dot-product head.
// R5: wave-per-node agg, x4 unroll, streamed norms, layer-1 reorder (SX)W.
//     Measured: 1476 us; agg<256> 252 us, byte-throughput-bound (hbm 3.8 TB/s,
//     VALU 10.7%, FETCH 833 MB of 1.85 GB demanded).
// R8: bf16 data plane. All gather tables + GEMM in/out are bf16 (fp32 accum,
//     fp32 weights/biases, final agg writes fp32 for predictor). Halves bytes
//     at every cache tier for the gather-bound aggs; GEMM stages bf16 too.
// R9: resubmit unchanged (R8 never ran — broker timeout).
// Flow (B0,B1 = N x 256 bf16; F32 = N x 128 fp32):
//   conv x->B0 | agg128 B0->B1 | g1_256 B1->B0 (+b1) | g2_256 B0->B1 |
//   agg256 B1->B0 (+b2) | g3_128 B0->B1 | agg128 B1->F32 (+b3) | pred(F32)
// ---------------------------------------------------------------------------

__device__ __forceinline__ float bf2f(unsigned int u16) {
  union { unsigned int i; float f; } v; v.i = u16 << 16; return v.f;
}
__device__ __forceinline__ unsigned short f2bf(float f) {
  union { float f; unsigned int u; } v; v.f = f;
  unsigned int r = v.u + 0x7fffu + ((v.u >> 16) & 1u);   // RNE
  return (unsigned short)(r >> 16);
}
__device__ __forceinline__ float4 ld_bf4(const unsigned short* p) {   // 8B aligned
  uint2 u = *reinterpret_cast<const uint2*>(p);
  float4 r; r.x = bf2f(u.x & 0xFFFFu); r.y = bf2f(u.x >> 16);
  r.z = bf2f(u.y & 0xFFFFu); r.w = bf2f(u.y >> 16); return r;
}
__device__ __forceinline__ float2 ld_bf2(const unsigned short* p) {   // 4B aligned
  unsigned int u = *reinterpret_cast<const unsigned int*>(p);
  return make_float2(bf2f(u & 0xFFFFu), bf2f(u >> 16));
}
__device__ __forceinline__ void st_bf4(unsigned short* p, float4 v) {
  uint2 u; u.x = (unsigned int)f2bf(v.x) | ((unsigned int)f2bf(v.y) << 16);
  u.y = (unsigned int)f2bf(v.z) | ((unsigned int)f2bf(v.w) << 16);
  *reinterpret_cast<uint2*>(p) = u;
}
__device__ __forceinline__ void st_bf2(unsigned short* p, float2 v) {
  unsigned int u = (unsigned int)f2bf(v.x) | ((unsigned int)f2bf(v.y) << 16);
  *reinterpret_cast<unsigned int*>(p) = u;
}
__device__ __forceinline__ float4 f4fma(float4 a, float s, float4 c) {
  c.x = fmaf(a.x, s, c.x); c.y = fmaf(a.y, s, c.y);
  c.z = fmaf(a.z, s, c.z); c.w = fmaf(a.w, s, c.w); return c;
}
__device__ __forceinline__ float2 f2fma(float2 a, float s, float2 c) {
  c.x = fmaf(a.x, s, c.x); c.y = fmaf(a.y, s, c.y); return c;
}

// --- dtype probe: even bf16-view elements of fp32 data have random exponents.
__global__ void k_detect(const unsigned short* __restrict__ xh, int* flag) {
  __shared__ int cnt_s;
  if (threadIdx.x == 0) cnt_s = 0;
  __syncthreads();
  int huge = 0;
  for (int j = 0; j < 16; ++j) {
    unsigned short u = xh[2 * (threadIdx.x * 16 + j)];
    int e = (u >> 7) & 0xFF;
    if (e > 137) huge++;                 // |v| > 2^10: impossible for N(0,1) bf16
  }
  atomicAdd(&cnt_s, huge);
  __syncthreads();
  if (threadIdx.x == 0) flag[0] = (cnt_s > 512) ? 1 : 0;   // 1 => fp32 storage
}

__global__ void k_convert(const void* __restrict__ src, float* __restrict__ dst,
                          int n, const int* __restrict__ flagp) {
  const int fp32 = flagp[0];
  int i = blockIdx.x * blockDim.x + threadIdx.x;
  const int stride = gridDim.x * blockDim.x;
  if (fp32) {
    const float* s = (const float*)src;
    for (; i < n; i += stride) dst[i] = s[i];
  } else {
    const unsigned short* s = (const unsigned short*)src;
    for (; i < n; i += stride) dst[i] = bf2f(s[i]);
  }
}

// x -> bf16 table
__global__ void k_conv16(const void* __restrict__ src, unsigned short* __restrict__ dst,
                         int n, const int* __restrict__ flagp) {
  const int fp32 = flagp[0];
  int i = blockIdx.x * blockDim.x + threadIdx.x;
  const int stride = gridDim.x * blockDim.x;
  if (fp32) {
    const float* s = (const float*)src;
    for (; i < n; i += stride) dst[i] = f2bf(s[i]);
  } else {
    const unsigned short* s = (const unsigned short*)src;
    for (; i < n; i += stride) dst[i] = s[i];
  }
}

__global__ void k_deg(const int* __restrict__ dst, int E, int* __restrict__ cnt) {
  int i = blockIdx.x * blockDim.x + threadIdx.x;
  const int stride = gridDim.x * blockDim.x;
  for (; i < E; i += stride) atomicAdd(&cnt[dst[i]], 1);
}

__global__ void k_dinv(const int* __restrict__ cnt, float* __restrict__ dinv, int N) {
  int i = blockIdx.x * blockDim.x + threadIdx.x;
  if (i < N) dinv[i] = 1.0f / sqrtf((float)(cnt[i] + 1));   // +1 self-loop
}

// single-block exclusive scan
__global__ void k_scan(const int* __restrict__ cnt, int* __restrict__ rowptr, int n) {
  __shared__ int s[1024];
  const int t = threadIdx.x;
  const int chunk = (n + 1023) >> 10;
  const int b = t * chunk;
  const int e = min(b + chunk, n);
  int sum = 0;
  for (int i = b; i < e; ++i) sum += cnt[i];
  s[t] = sum;
  __syncthreads();
  for (int off = 1; off < 1024; off <<= 1) {
    int add = (t >= off) ? s[t - off] : 0;
    __syncthreads();
    s[t] += add;
    __syncthreads();
  }
  int run = s[t] - sum;
  for (int i = b; i < e; ++i) { rowptr[i] = run; run += cnt[i]; }
  if (t == 1023) rowptr[n] = s[1023];
}

__global__ void k_fill(const int* __restrict__ src, const int* __restrict__ dst, int E,
                       const int* __restrict__ rowptr, int* __restrict__ cursor,
                       const float* __restrict__ dinv,
                       int* __restrict__ csr_src, float* __restrict__ csr_nrm) {
  int i = blockIdx.x * blockDim.x + threadIdx.x;
  const int stride = gridDim.x * blockDim.x;
  for (; i < E; i += stride) {
    const int d = dst[i];
    const int s = src[i];
    const int pos = rowptr[d] + atomicAdd(&cursor[d], 1);
    csr_src[pos] = s;
    csr_nrm[pos] = dinv[s];
  }
}

// --- tiled GEMM, bf16 in / bf16 out, fp32 compute:
// out[N][FOUT] = bf16( in[N][Fin] @ W[Fin][FOUT] (+ bias) )
template <int FOUT>
__global__ __launch_bounds__(256) void k_gemm(
    const unsigned short* __restrict__ in16, int Fin, int N,
    const float* __restrict__ W, const float* __restrict__ bias,
    unsigned short* __restrict__ out16) {
  constexpr int NJ = FOUT / 64;
  __shared__ float Ws[32 * FOUT];
  __shared__ float XsT[32 * 64];            // [k][r]
  const int t = threadIdx.x;
  const int r0 = blockIdx.x * 64;
  const int tc = t & 63;
  const int tr = t >> 6;

  float acc[16][NJ];
#pragma unroll
  for (int i = 0; i < 16; ++i)
#pragma unroll
    for (int j = 0; j < NJ; ++j) acc[i][j] = 0.f;

  for (int k0 = 0; k0 < Fin; k0 += 32) {
    {   // stage X^T: each thread 8 bf16 (16B) of one row
      const int r = t >> 2;
      const int ks = (t & 3) * 8;
      const int grow = r0 + r;
      if (grow < N) {
        const uint4 raw = *reinterpret_cast<const uint4*>(
            in16 + (size_t)grow * Fin + k0 + ks);
        XsT[(ks + 0) * 64 + r] = bf2f(raw.x & 0xFFFFu);
        XsT[(ks + 1) * 64 + r] = bf2f(raw.x >> 16);
        XsT[(ks + 2) * 64 + r] = bf2f(raw.y & 0xFFFFu);
        XsT[(ks + 3) * 64 + r] = bf2f(raw.y >> 16);
        XsT[(ks + 4) * 64 + r] = bf2f(raw.z & 0xFFFFu);
        XsT[(ks + 5) * 64 + r] = bf2f(raw.z >> 16);
        XsT[(ks + 6) * 64 + r] = bf2f(raw.w & 0xFFFFu);
        XsT[(ks + 7) * 64 + r] = bf2f(raw.w >> 16);
      } else {
#pragma unroll
        for (int j = 0; j < 8; ++j) XsT[(ks + j) * 64 + r] = 0.f;
      }
    }
    {   // stage W tile [32][FOUT]
#pragma unroll
      for (int p = 0; p < FOUT / 8; ++p) {
        const int idx = t + 256 * p;
        const int k = idx / FOUT, c = idx % FOUT;
        Ws[idx] = W[(size_t)(k0 + k) * FOUT + c];
      }
    }
    __syncthreads();
    for (int k = 0; k < 32; ++k) {
      const float4* xr = reinterpret_cast<const float4*>(&XsT[k * 64 + tr * 16]);
      const float4 a0 = xr[0], a1 = xr[1], a2 = xr[2], a3 = xr[3];
      const float xv[16] = {a0.x, a0.y, a0.z, a0.w, a1.x, a1.y, a1.z, a1.w,
                            a2.x, a2.y, a2.z, a2.w, a3.x, a3.y, a3.z, a3.w};
      float wv[NJ];
#pragma unroll
      for (int j = 0; j < NJ; ++j) wv[j] = Ws[k * FOUT + tc + 64 * j];
#pragma unroll
      for (int i = 0; i < 16; ++i)
#pragma unroll
        for (int j = 0; j < NJ; ++j) acc[i][j] = fmaf(xv[i], wv[j], acc[i][j]);
    }
    __syncthreads();
  }
#pragma unroll
  for (int i = 0; i < 16; ++i) {
    const int r = r0 + tr * 16 + i;
    if (r < N) {
#pragma unroll
      for (int j = 0; j < NJ; ++j) {
        const int c = tc + 64 * j;
        out16[(size_t)r * FOUT + c] = f2bf(acc[i][j] + (bias ? bias[c] : 0.f));
      }
    }
  }
}

// --- gather aggregation over bf16 table, fp32 accum, x4 unroll:
// H[d] = sum_{s in CSR[d]} T[s]*nrm[s]*di + T[d]*di^2 (+ bias)
// F32OUT: write fp32 (for predictor), else bf16.
template <int FOUT, bool F32OUT>
__global__ __launch_bounds__(256) void k_agg(
    const unsigned short* __restrict__ T16, void* __restrict__ Hout,
    const float* __restrict__ dinv, const int* __restrict__ rowptr,
    const int* __restrict__ csr_src, const float* __restrict__ csr_nrm,
    const float* __restrict__ bias, int N) {
  const int lane = threadIdx.x & 63;
  const int node = blockIdx.x * 4 + (threadIdx.x >> 6);
  if (node >= N) return;
  const float di = dinv[node];
  const int jb = rowptr[node], je = rowptr[node + 1];

  if constexpr (FOUT == 256) {
    const unsigned short* __restrict__ base = T16;
    float4 acc = ld_bf4(base + (size_t)node * 256 + lane * 4);
    acc.x *= di * di; acc.y *= di * di; acc.z *= di * di; acc.w *= di * di;
    int j = jb;
    for (; j + 4 <= je; j += 4) {
      const int s0 = csr_src[j], s1 = csr_src[j + 1],
                s2 = csr_src[j + 2], s3 = csr_src[j + 3];
      const float n0 = csr_nrm[j] * di, n1 = csr_nrm[j + 1] * di,
                  n2 = csr_nrm[j + 2] * di, n3 = csr_nrm[j + 3] * di;
      const float4 r0 = ld_bf4(base + (size_t)s0 * 256 + lane * 4);
      const float4 r1 = ld_bf4(base + (size_t)s1 * 256 + lane * 4);
      const float4 r2 = ld_bf4(base + (size_t)s2 * 256 + lane * 4);
      const float4 r3 = ld_bf4(base + (size_t)s3 * 256 + lane * 4);
      acc = f4fma(r0, n0, acc); acc = f4fma(r1, n1, acc);
      acc = f4fma(r2, n2, acc); acc = f4fma(r3, n3, acc);
    }
    for (; j < je; ++j)
      acc = f4fma(ld_bf4(base + (size_t)csr_src[j] * 256 + lane * 4),
                  csr_nrm[j] * di, acc);
    if (bias) {
      const float4 b = ((const float4*)bias)[lane];
      acc.x += b.x; acc.y += b.y; acc.z += b.z; acc.w += b.w;
    }
    if constexpr (F32OUT)
      ((float4*)Hout)[(size_t)node * 64 + lane] = acc;
    else
      st_bf4((unsigned short*)Hout + (size_t)node * 256 + lane * 4, acc);
  } else {                                   // FOUT == 128
    const unsigned short* __restrict__ base = T16;
    float2 acc = ld_bf2(base + (size_t)node * 128 + lane * 2);
    acc.x *= di * di; acc.y *= di * di;
    int j = jb;
    for (; j + 4 <= je; j += 4) {
      const int s0 = csr_src[j], s1 = csr_src[j + 1],
                s2 = csr_src[j + 2], s3 = csr_src[j + 3];
      const float n0 = csr_nrm[j] * di, n1 = csr_nrm[j + 1] * di,
                  n2 = csr_nrm[j + 2] * di, n3 = csr_nrm[j + 3] * di;
      const float2 r0 = ld_bf2(base + (size_t)s0 * 128 + lane * 2);
      const float2 r1 = ld_bf2(base + (size_t)s1 * 128 + lane * 2);
      const float2 r2 = ld_bf2(base + (size_t)s2 * 128 + lane * 2);
      const float2 r3 = ld_bf2(base + (size_t)s3 * 128 + lane * 2);
      acc = f2fma(r0, n0, acc); acc = f2fma(r1, n1, acc);
      acc = f2fma(r2, n2, acc); acc = f2fma(r3, n3, acc);
    }
    for (; j < je; ++j)
      acc = f2fma(ld_bf2(base + (size_t)csr_src[j] * 128 + lane * 2),
                  csr_nrm[j] * di, acc);
    if (bias) {
      const float2 b = ((const float2*)bias)[lane];
      acc.x += b.x; acc.y += b.y;
    }
    if constexpr (F32OUT)
      ((float2*)Hout)[(size_t)node * 64 + lane] = acc;
    else
      st_bf2((unsigned short*)Hout + (size_t)node * 128 + lane * 2, acc);
  }
}

// --- predictor: out[i] = sum_f H[a][f]*H[b][f]*Wp[f] + bp   (fp32 in/out)
__global__ __launch_bounds__(256) void k_pred(
    const float* __restrict__ H, const int* __restrict__ eli, int L,
    const float* __restrict__ Wp, const float* __restrict__ bp,
    float* __restrict__ out) {
  __shared__ float wp_s[128];
  if (threadIdx.x < 128) wp_s[threadIdx.x] = Wp[threadIdx.x];
  __syncthreads();
  const int i = blockIdx.x * 256 + threadIdx.x;
  if (i >= L) return;
  const int a = eli[i], b = eli[L + i];
  const float4* ha = reinterpret_cast<const float4*>(H + (size_t)a * 128);
  const float4* hb = reinterpret_cast<const float4*>(H + (size_t)b * 128);
  const float4* wp4 = reinterpret_cast<const float4*>(wp_s);
  float acc = 0.f;
#pragma unroll
  for (int q = 0; q < 32; ++q) {
    const float4 x = ha[q], y = hb[q], w = wp4[q];
    acc += x.x * y.x * w.x + x.y * y.y * w.y + x.z * y.z * w.z + x.w * y.w * w.w;
  }
  out[i] = acc + bp[0];
}

extern "C" void kernel_launch(void* const* d_in, const int* in_sizes, int n_in,
                              void* d_out, int out_size, void* d_ws, size_t ws_size,
                              hipStream_t stream) {
  (void)n_in; (void)out_size; (void)ws_size;
  const void* x   = d_in[0];
  const int*  ei  = (const int*)d_in[1];   // [2][E]: src row 0, dst row 1
  const int*  eli = (const int*)d_in[2];   // [2][L]
  const int N = in_sizes[0] / 128;
  const int E = in_sizes[1] / 2;
  const int L = in_sizes[2] / 2;

  // workspace carve-out (256B aligned); total ~170 MB
  char* p = (char*)d_ws;
  auto alloc = [&](size_t bytes) -> char* {
    char* r = p; p += (bytes + 255) & ~(size_t)255; return r;
  };
  int*            flag    = (int*)            alloc(256);
  float*          wf      = (float*)          alloc((size_t)131841 * 4);
  int*            cnt     = (int*)            alloc((size_t)N * 4);
  int*            rowptr  = (int*)            alloc(((size_t)N + 1) * 4);
  int*            cursor  = (int*)            alloc((size_t)N * 4);
  float*          dinv    = (float*)          alloc((size_t)N * 4);
  int*            csr_src = (int*)            alloc((size_t)E * 4);
  float*          csr_nrm = (float*)          alloc((size_t)E * 4);
  unsigned short* B0      = (unsigned short*) alloc((size_t)N * 256 * 2);
  unsigned short* B1      = (unsigned short*) alloc((size_t)N * 256 * 2);
  float*          F32out  = (float*)          alloc((size_t)N * 128 * 4);

  // weight layout inside wf (float offsets)
  const int OW1 = 0, OB1 = 32768, OW2 = 33024, OB2 = 98560,
            OW3 = 98816, OB3 = 131584, OWP = 131712, OBP = 131840;

  hipMemsetAsync(flag, 0, 256, stream);
  hipMemsetAsync(cnt, 0, (size_t)N * 4, stream);
  hipMemsetAsync(cursor, 0, (size_t)N * 4, stream);

  k_detect<<<1, 256, 0, stream>>>((const unsigned short*)x, flag);

  const int   widx[8] = {3, 4, 5, 6, 7, 8, 9, 10};
  const int   woff[8] = {OW1, OB1, OW2, OB2, OW3, OB3, OWP, OBP};
  const int   wcnt[8] = {32768, 256, 65536, 256, 32768, 128, 128, 1};
  for (int i = 0; i < 8; ++i) {
    int grid = (wcnt[i] + 255) / 256; if (grid > 256) grid = 256;
    k_convert<<<grid, 256, 0, stream>>>(d_in[widx[i]], wf + woff[i], wcnt[i], flag);
  }
  // x -> bf16 table in B0 (N x 128)
  k_conv16<<<2048, 256, 0, stream>>>(x, B0, N * 128, flag);

  k_deg<<<2048, 256, 0, stream>>>(ei + E, E, cnt);
  k_dinv<<<(N + 255) / 256, 256, 0, stream>>>(cnt, dinv, N);
  k_scan<<<1, 1024, 0, stream>>>(cnt, rowptr, N);
  k_fill<<<2048, 256, 0, stream>>>(ei, ei + E, E, rowptr, cursor, dinv,
                                   csr_src, csr_nrm);

  const int ggrid = (N + 63) / 64;
  const int agrid = (N + 3) / 4;
  // layer 1 (reordered): agg(x) 128 cols -> B1, then GEMM(+b1) -> B0
  k_agg<128, false><<<agrid, 256, 0, stream>>>(B0, B1, dinv, rowptr, csr_src,
                                               csr_nrm, nullptr, N);
  k_gemm<256><<<ggrid, 256, 0, stream>>>(B1, 128, N, wf + OW1, wf + OB1, B0);
  // layer 2: GEMM -> B1, agg(+b2) -> B0
  k_gemm<256><<<ggrid, 256, 0, stream>>>(B0, 256, N, wf + OW2, nullptr, B1);
  k_agg<256, false><<<agrid, 256, 0, stream>>>(B1, B0, dinv, rowptr, csr_src,
                                               csr_nrm, wf + OB2, N);
  // layer 3: GEMM -> B1 (128), agg(+b3) -> F32out
  k_gemm<128><<<ggrid, 256, 0, stream>>>(B0, 256, N, wf + OW3, nullptr, B1);
  k_agg<128, true><<<agrid, 256, 0, stream>>>(B1, F32out, dinv, rowptr, csr_src,
                                              csr_nrm, wf + OB3, N);
  // predictor (fp32 out)
  k_pred<<<(L + 255) / 256, 256, 0, stream>>>(F32out, eli, L, wf + OWP, wf + OBP,
                                              (float*)d_out);
}

// Round 13
// 965.259 us; speedup vs baseline: 2.3780x; 1.2650x over previous
//
#include <hip/hip_runtime.h>

// ---------------------------------------------------------------------------
// GCN link predictor: 3x GCNConv (128->256->256->128) + edge dot-product head.
// R5:  wave-per-node agg (1476 us). R8: bf16 data plane (1221 us; aggs halved,
//      GEMMs now top: 189 us each, VALU-bound, MfmaUtil 0).
// R10: MFMA GEMM. LDS-free wave-GEMM on v_mfma_f32_16x16x32_bf16:
//      - A-frags: direct dwordx4 from row-major bf16 table (lane&15 = row,
//        (lane>>4)*8 = k offset) -- L1/L2-served, 8 waves share each strip.
//      - B-frags: k_wfrag pre-scatters W into per-lane fragment order once;
//        per-wave preload = KS*2 coalesced 16B loads, reused across strips.
//      - C/D layout (verified m89/m91): col=lane&15, row=(lane>>4)*4+reg.
//      Weights bf16 now (adds ~1.5e-3/layer decorrelated rounding).
// R11/R12: resubmit unchanged (R10 never ran — broker timeouts).
// Flow (B0,B1 = N x 256 bf16; F32 = N x 128 fp32):
//   conv x->B0 | agg128 B0->B1 | gmm<128,256,+b1> B1->B0 | gmm<256,256> B0->B1
//   | agg256 B1->B0 (+b2) | gmm<256,128> B0->B1 | agg128 B1->F32 (+b3) | pred
// ---------------------------------------------------------------------------

typedef __bf16 bf16x8 __attribute__((ext_vector_type(8)));
typedef float  f32x4  __attribute__((ext_vector_type(4)));

__device__ __forceinline__ float bf2f(unsigned int u16) {
  union { unsigned int i; float f; } v; v.i = u16 << 16; return v.f;
}
__device__ __forceinline__ unsigned short f2bf(float f) {
  union { float f; unsigned int u; } v; v.f = f;
  unsigned int r = v.u + 0x7fffu + ((v.u >> 16) & 1u);   // RNE
  return (unsigned short)(r >> 16);
}
__device__ __forceinline__ float4 ld_bf4(const unsigned short* p) {   // 8B aligned
  uint2 u = *reinterpret_cast<const uint2*>(p);
  float4 r; r.x = bf2f(u.x & 0xFFFFu); r.y = bf2f(u.x >> 16);
  r.z = bf2f(u.y & 0xFFFFu); r.w = bf2f(u.y >> 16); return r;
}
__device__ __forceinline__ float2 ld_bf2(const unsigned short* p) {   // 4B aligned
  unsigned int u = *reinterpret_cast<const unsigned int*>(p);
  return make_float2(bf2f(u & 0xFFFFu), bf2f(u >> 16));
}
__device__ __forceinline__ void st_bf4(unsigned short* p, float4 v) {
  uint2 u; u.x = (unsigned int)f2bf(v.x) | ((unsigned int)f2bf(v.y) << 16);
  u.y = (unsigned int)f2bf(v.z) | ((unsigned int)f2bf(v.w) << 16);
  *reinterpret_cast<uint2*>(p) = u;
}
__device__ __forceinline__ void st_bf2(unsigned short* p, float2 v) {
  unsigned int u = (unsigned int)f2bf(v.x) | ((unsigned int)f2bf(v.y) << 16);
  *reinterpret_cast<unsigned int*>(p) = u;
}
__device__ __forceinline__ float4 f4fma(float4 a, float s, float4 c) {
  c.x = fmaf(a.x, s, c.x); c.y = fmaf(a.y, s, c.y);
  c.z = fmaf(a.z, s, c.z); c.w = fmaf(a.w, s, c.w); return c;
}
__device__ __forceinline__ float2 f2fma(float2 a, float s, float2 c) {
  c.x = fmaf(a.x, s, c.x); c.y = fmaf(a.y, s, c.y); return c;
}

// --- dtype probe: even bf16-view elements of fp32 data have random exponents.
__global__ void k_detect(const unsigned short* __restrict__ xh, int* flag) {
  __shared__ int cnt_s;
  if (threadIdx.x == 0) cnt_s = 0;
  __syncthreads();
  int huge = 0;
  for (int j = 0; j < 16; ++j) {
    unsigned short u = xh[2 * (threadIdx.x * 16 + j)];
    int e = (u >> 7) & 0xFF;
    if (e > 137) huge++;                 // |v| > 2^10: impossible for N(0,1) bf16
  }
  atomicAdd(&cnt_s, huge);
  __syncthreads();
  if (threadIdx.x == 0) flag[0] = (cnt_s > 512) ? 1 : 0;   // 1 => fp32 storage
}

__global__ void k_convert(const void* __restrict__ src, float* __restrict__ dst,
                          int n, const int* __restrict__ flagp) {
  const int fp32 = flagp[0];
  int i = blockIdx.x * blockDim.x + threadIdx.x;
  const int stride = gridDim.x * blockDim.x;
  if (fp32) {
    const float* s = (const float*)src;
    for (; i < n; i += stride) dst[i] = s[i];
  } else {
    const unsigned short* s = (const unsigned short*)src;
    for (; i < n; i += stride) dst[i] = bf2f(s[i]);
  }
}

// x -> bf16 table
__global__ void k_conv16(const void* __restrict__ src, unsigned short* __restrict__ dst,
                         int n, const int* __restrict__ flagp) {
  const int fp32 = flagp[0];
  int i = blockIdx.x * blockDim.x + threadIdx.x;
  const int stride = gridDim.x * blockDim.x;
  if (fp32) {
    const float* s = (const float*)src;
    for (; i < n; i += stride) dst[i] = f2bf(s[i]);
  } else {
    const unsigned short* s = (const unsigned short*)src;
    for (; i < n; i += stride) dst[i] = s[i];
  }
}

// W[K][FOUT] -> per-lane MFMA B-fragment order:
// dst[((tn*KS + ks)*64 + lane)*8 + j] = bf16( W[ks*32+(lane>>4)*8+j][tn*16+(lane&15)] )
__global__ void k_wfrag(const void* __restrict__ src, unsigned short* __restrict__ dst,
                        int FOUT, int KS, int nelem, const int* __restrict__ flagp) {
  const int fp32 = flagp[0];
  int tid = blockIdx.x * blockDim.x + threadIdx.x;
  const int stride = gridDim.x * blockDim.x;
  for (; tid < nelem; tid += stride) {
    const int j = tid & 7;
    const int lane = (tid >> 3) & 63;
    const int rest = tid >> 9;
    const int ks = rest % KS;
    const int tn = rest / KS;
    const int k = ks * 32 + (lane >> 4) * 8 + j;
    const int c = tn * 16 + (lane & 15);
    const size_t si = (size_t)k * FOUT + c;
    dst[tid] = fp32 ? f2bf(((const float*)src)[si])
                    : ((const unsigned short*)src)[si];
  }
}

__global__ void k_deg(const int* __restrict__ dst, int E, int* __restrict__ cnt) {
  int i = blockIdx.x * blockDim.x + threadIdx.x;
  const int stride = gridDim.x * blockDim.x;
  for (; i < E; i += stride) atomicAdd(&cnt[dst[i]], 1);
}

__global__ void k_dinv(const int* __restrict__ cnt, float* __restrict__ dinv, int N) {
  int i = blockIdx.x * blockDim.x + threadIdx.x;
  if (i < N) dinv[i] = 1.0f / sqrtf((float)(cnt[i] + 1));   // +1 self-loop
}

// single-block exclusive scan
__global__ void k_scan(const int* __restrict__ cnt, int* __restrict__ rowptr, int n) {
  __shared__ int s[1024];
  const int t = threadIdx.x;
  const int chunk = (n + 1023) >> 10;
  const int b = t * chunk;
  const int e = min(b + chunk, n);
  int sum = 0;
  for (int i = b; i < e; ++i) sum += cnt[i];
  s[t] = sum;
  __syncthreads();
  for (int off = 1; off < 1024; off <<= 1) {
    int add = (t >= off) ? s[t - off] : 0;
    __syncthreads();
    s[t] += add;
    __syncthreads();
  }
  int run = s[t] - sum;
  for (int i = b; i < e; ++i) { rowptr[i] = run; run += cnt[i]; }
  if (t == 1023) rowptr[n] = s[1023];
}

__global__ void k_fill(const int* __restrict__ src, const int* __restrict__ dst, int E,
                       const int* __restrict__ rowptr, int* __restrict__ cursor,
                       const float* __restrict__ dinv,
                       int* __restrict__ csr_src, float* __restrict__ csr_nrm) {
  int i = blockIdx.x * blockDim.x + threadIdx.x;
  const int stride = gridDim.x * blockDim.x;
  for (; i < E; i += stride) {
    const int d = dst[i];
    const int s = src[i];
    const int pos = rowptr[d] + atomicAdd(&cursor[d], 1);
    csr_src[pos] = s;
    csr_nrm[pos] = dinv[s];
  }
}

// --- LDS-free MFMA GEMM: C[N][FOUT] = bf16( A[N][FIN] @ W (+bias) )
// Wave w: 16-row strips (grid-stride) x 32-col strip (cstrip = w % (FOUT/32)).
// A-frag: lane reads A[s*16 + (lane&15)][ks*32 + (lane>>4)*8 .. +7]  (16B).
// B-frag: preloaded from k_wfrag table, 2 tiles x KS, registers.
template <int FIN, int FOUT, bool BIAS>
__global__ __launch_bounds__(256) void k_gmm(
    const unsigned short* __restrict__ A, const unsigned short* __restrict__ Wf,
    const float* __restrict__ bias, unsigned short* __restrict__ C, int N) {
  constexpr int KS = FIN / 32;
  constexpr int CS = FOUT / 32;
  const int lane = threadIdx.x & 63;
  const int wid = (blockIdx.x * 256 + threadIdx.x) >> 6;
  const int nwaves = (gridDim.x * 256) >> 6;
  const int cstrip = wid & (CS - 1);
  const int strip0 = wid / CS;
  const int sstride = nwaves / CS;
  const int nstrips = (N + 15) >> 4;
  const int col0 = cstrip * 32;

  bf16x8 bfrag[2][KS];
#pragma unroll
  for (int t = 0; t < 2; ++t)
#pragma unroll
    for (int ks = 0; ks < KS; ++ks) {
      const size_t idx = ((size_t)((col0 / 16 + t) * KS + ks) * 64 + lane) * 8;
      bfrag[t][ks] = *reinterpret_cast<const bf16x8*>(Wf + idx);
    }
  float b0 = 0.f, b1 = 0.f;
  if (BIAS) {
    b0 = bias[col0 + (lane & 15)];
    b1 = bias[col0 + 16 + (lane & 15)];
  }

  for (int s = strip0; s < nstrips; s += sstride) {
    const int r0 = s * 16;
    const unsigned short* arow =
        A + (size_t)(r0 + (lane & 15)) * FIN + (lane >> 4) * 8;
    f32x4 acc0 = {0.f, 0.f, 0.f, 0.f};
    f32x4 acc1 = {0.f, 0.f, 0.f, 0.f};
#pragma unroll
    for (int ks = 0; ks < KS; ++ks) {
      const bf16x8 af = *reinterpret_cast<const bf16x8*>(arow + ks * 32);
      acc0 = __builtin_amdgcn_mfma_f32_16x16x32_bf16(af, bfrag[0][ks], acc0, 0, 0, 0);
      acc1 = __builtin_amdgcn_mfma_f32_16x16x32_bf16(af, bfrag[1][ks], acc1, 0, 0, 0);
    }
    const int rr = r0 + 4 * (lane >> 4);
    unsigned short* cp = C + (size_t)rr * FOUT + col0 + (lane & 15);
#pragma unroll
    for (int r = 0; r < 4; ++r) {
      if (rr + r < N) {
        cp[(size_t)r * FOUT] = f2bf(acc0[r] + b0);
        cp[(size_t)r * FOUT + 16] = f2bf(acc1[r] + b1);
      }
    }
  }
}

// --- gather aggregation over bf16 table, fp32 accum, x4 unroll
template <int FOUT, bool F32OUT>
__global__ __launch_bounds__(256) void k_agg(
    const unsigned short* __restrict__ T16, void* __restrict__ Hout,
    const float* __restrict__ dinv, const int* __restrict__ rowptr,
    const int* __restrict__ csr_src, const float* __restrict__ csr_nrm,
    const float* __restrict__ bias, int N) {
  const int lane = threadIdx.x & 63;
  const int node = blockIdx.x * 4 + (threadIdx.x >> 6);
  if (node >= N) return;
  const float di = dinv[node];
  const int jb = rowptr[node], je = rowptr[node + 1];

  if constexpr (FOUT == 256) {
    const unsigned short* __restrict__ base = T16;
    float4 acc = ld_bf4(base + (size_t)node * 256 + lane * 4);
    acc.x *= di * di; acc.y *= di * di; acc.z *= di * di; acc.w *= di * di;
    int j = jb;
    for (; j + 4 <= je; j += 4) {
      const int s0 = csr_src[j], s1 = csr_src[j + 1],
                s2 = csr_src[j + 2], s3 = csr_src[j + 3];
      const float n0 = csr_nrm[j] * di, n1 = csr_nrm[j + 1] * di,
                  n2 = csr_nrm[j + 2] * di, n3 = csr_nrm[j + 3] * di;
      const float4 r0 = ld_bf4(base + (size_t)s0 * 256 + lane * 4);
      const float4 r1 = ld_bf4(base + (size_t)s1 * 256 + lane * 4);
      const float4 r2 = ld_bf4(base + (size_t)s2 * 256 + lane * 4);
      const float4 r3 = ld_bf4(base + (size_t)s3 * 256 + lane * 4);
      acc = f4fma(r0, n0, acc); acc = f4fma(r1, n1, acc);
      acc = f4fma(r2, n2, acc); acc = f4fma(r3, n3, acc);
    }
    for (; j < je; ++j)
      acc = f4fma(ld_bf4(base + (size_t)csr_src[j] * 256 + lane * 4),
                  csr_nrm[j] * di, acc);
    if (bias) {
      const float4 b = ((const float4*)bias)[lane];
      acc.x += b.x; acc.y += b.y; acc.z += b.z; acc.w += b.w;
    }
    if constexpr (F32OUT)
      ((float4*)Hout)[(size_t)node * 64 + lane] = acc;
    else
      st_bf4((unsigned short*)Hout + (size_t)node * 256 + lane * 4, acc);
  } else {                                   // FOUT == 128
    const unsigned short* __restrict__ base = T16;
    float2 acc = ld_bf2(base + (size_t)node * 128 + lane * 2);
    acc.x *= di * di; acc.y *= di * di;
    int j = jb;
    for (; j + 4 <= je; j += 4) {
      const int s0 = csr_src[j], s1 = csr_src[j + 1],
                s2 = csr_src[j + 2], s3 = csr_src[j + 3];
      const float n0 = csr_nrm[j] * di, n1 = csr_nrm[j + 1] * di,
                  n2 = csr_nrm[j + 2] * di, n3 = csr_nrm[j + 3] * di;
      const float2 r0 = ld_bf2(base + (size_t)s0 * 128 + lane * 2);
      const float2 r1 = ld_bf2(base + (size_t)s1 * 128 + lane * 2);
      const float2 r2 = ld_bf2(base + (size_t)s2 * 128 + lane * 2);
      const float2 r3 = ld_bf2(base + (size_t)s3 * 128 + lane * 2);
      acc = f2fma(r0, n0, acc); acc = f2fma(r1, n1, acc);
      acc = f2fma(r2, n2, acc); acc = f2fma(r3, n3, acc);
    }
    for (; j < je; ++j)
      acc = f2fma(ld_bf2(base + (size_t)csr_src[j] * 128 + lane * 2),
                  csr_nrm[j] * di, acc);
    if (bias) {
      const float2 b = ((const float2*)bias)[lane];
      acc.x += b.x; acc.y += b.y;
    }
    if constexpr (F32OUT)
      ((float2*)Hout)[(size_t)node * 64 + lane] = acc;
    else
      st_bf2((unsigned short*)Hout + (size_t)node * 128 + lane * 2, acc);
  }
}

// --- predictor: out[i] = sum_f H[a][f]*H[b][f]*Wp[f] + bp   (fp32 in/out)
__global__ __launch_bounds__(256) void k_pred(
    const float* __restrict__ H, const int* __restrict__ eli, int L,
    const float* __restrict__ Wp, const float* __restrict__ bp,
    float* __restrict__ out) {
  __shared__ float wp_s[128];
  if (threadIdx.x < 128) wp_s[threadIdx.x] = Wp[threadIdx.x];
  __syncthreads();
  const int i = blockIdx.x * 256 + threadIdx.x;
  if (i >= L) return;
  const int a = eli[i], b = eli[L + i];
  const float4* ha = reinterpret_cast<const float4*>(H + (size_t)a * 128);
  const float4* hb = reinterpret_cast<const float4*>(H + (size_t)b * 128);
  const float4* wp4 = reinterpret_cast<const float4*>(wp_s);
  float acc = 0.f;
#pragma unroll
  for (int q = 0; q < 32; ++q) {
    const float4 x = ha[q], y = hb[q], w = wp4[q];
    acc += x.x * y.x * w.x + x.y * y.y * w.y + x.z * y.z * w.z + x.w * y.w * w.w;
  }
  out[i] = acc + bp[0];
}

extern "C" void kernel_launch(void* const* d_in, const int* in_sizes, int n_in,
                              void* d_out, int out_size, void* d_ws, size_t ws_size,
                              hipStream_t stream) {
  (void)n_in; (void)out_size; (void)ws_size;
  const void* x   = d_in[0];
  const int*  ei  = (const int*)d_in[1];   // [2][E]: src row 0, dst row 1
  const int*  eli = (const int*)d_in[2];   // [2][L]
  const int N = in_sizes[0] / 128;
  const int E = in_sizes[1] / 2;
  const int L = in_sizes[2] / 2;

  // workspace carve-out (256B aligned); total ~170 MB
  char* p = (char*)d_ws;
  auto alloc = [&](size_t bytes) -> char* {
    char* r = p; p += (bytes + 255) & ~(size_t)255; return r;
  };
  int*            flag    = (int*)            alloc(256);
  float*          wf      = (float*)          alloc((size_t)131841 * 4);
  unsigned short* wfrag1  = (unsigned short*) alloc((size_t)32768 * 2);
  unsigned short* wfrag2  = (unsigned short*) alloc((size_t)65536 * 2);
  unsigned short* wfrag3  = (unsigned short*) alloc((size_t)32768 * 2);
  int*            cnt     = (int*)            alloc((size_t)N * 4);
  int*            rowptr  = (int*)            alloc(((size_t)N + 1) * 4);
  int*            cursor  = (int*)            alloc((size_t)N * 4);
  float*          dinv    = (float*)          alloc((size_t)N * 4);
  int*            csr_src = (int*)            alloc((size_t)E * 4);
  float*          csr_nrm = (float*)          alloc((size_t)E * 4);
  unsigned short* B0      = (unsigned short*) alloc((size_t)N * 256 * 2);
  unsigned short* B1      = (unsigned short*) alloc((size_t)N * 256 * 2);
  float*          F32out  = (float*)          alloc((size_t)N * 128 * 4);

  // fp32 slots inside wf (float offsets): biases + predictor weights only
  const int OB1 = 32768, OB2 = 98560, OB3 = 131584, OWP = 131712, OBP = 131840;

  hipMemsetAsync(flag, 0, 256, stream);
  hipMemsetAsync(cnt, 0, (size_t)N * 4, stream);
  hipMemsetAsync(cursor, 0, (size_t)N * 4, stream);

  k_detect<<<1, 256, 0, stream>>>((const unsigned short*)x, flag);

  // biases + Wp + bp -> fp32
  const int widx[5] = {4, 6, 8, 9, 10};
  const int woff[5] = {OB1, OB2, OB3, OWP, OBP};
  const int wcnt[5] = {256, 256, 128, 128, 1};
  for (int i = 0; i < 5; ++i) {
    int grid = (wcnt[i] + 255) / 256; if (grid > 256) grid = 256;
    k_convert<<<grid, 256, 0, stream>>>(d_in[widx[i]], wf + woff[i], wcnt[i], flag);
  }
  // W1/W2/W3 -> MFMA fragment tables (bf16)
  k_wfrag<<<128, 256, 0, stream>>>(d_in[3], wfrag1, 256, 4, 32768, flag);
  k_wfrag<<<256, 256, 0, stream>>>(d_in[5], wfrag2, 256, 8, 65536, flag);
  k_wfrag<<<128, 256, 0, stream>>>(d_in[7], wfrag3, 128, 8, 32768, flag);
  // x -> bf16 table in B0 (N x 128)
  k_conv16<<<2048, 256, 0, stream>>>(x, B0, N * 128, flag);

  k_deg<<<2048, 256, 0, stream>>>(ei + E, E, cnt);
  k_dinv<<<(N + 255) / 256, 256, 0, stream>>>(cnt, dinv, N);
  k_scan<<<1, 1024, 0, stream>>>(cnt, rowptr, N);
  k_fill<<<2048, 256, 0, stream>>>(ei, ei + E, E, rowptr, cursor, dinv,
                                   csr_src, csr_nrm);

  const int agrid = (N + 3) / 4;
  const int ggrid = 1024;                      // 4096 waves
  // layer 1 (reordered): agg(x) 128 cols -> B1, then MFMA GEMM(+b1) -> B0
  k_agg<128, false><<<agrid, 256, 0, stream>>>(B0, B1, dinv, rowptr, csr_src,
                                               csr_nrm, nullptr, N);
  k_gmm<128, 256, true><<<ggrid, 256, 0, stream>>>(B1, wfrag1, wf + OB1, B0, N);
  // layer 2: GEMM -> B1, agg(+b2) -> B0
  k_gmm<256, 256, false><<<ggrid, 256, 0, stream>>>(B0, wfrag2, nullptr, B1, N);
  k_agg<256, false><<<agrid, 256, 0, stream>>>(B1, B0, dinv, rowptr, csr_src,
                                               csr_nrm, wf + OB2, N);
  // layer 3: GEMM -> B1 (128 cols), agg(+b3) -> F32out
  k_gmm<256, 128, false><<<ggrid, 256, 0, stream>>>(B0, wfrag3, nullptr, B1, N);
  k_agg<128, true><<<agrid, 256, 0, stream>>>(B1, F32out, dinv, rowptr, csr_src,
                                              csr_nrm, wf + OB3, N);
  // predictor (fp32 out)
  k_pred<<<(L + 255) / 256, 256, 0, stream>>>(F32out, eli, L, wf + OWP, wf + OBP,
                                              (float*)d_out);
}